// Round 2
// baseline (209.003 us; speedup 1.0000x reference)
//
#include <hip/hip_runtime.h>
#include <hip/hip_cooperative_groups.h>
#include <math.h>

namespace cg = cooperative_groups;

#define NN 1024
#define MM 1024
#define DD 256
#define TILE 64
#define NTB 16  // tiles per dimension

__device__ inline void merge_ms(float& m, float& s, float m2, float s2) {
  float mn = fmaxf(m, m2);
  s = s * __expf(m - mn) + s2 * __expf(m2 - mn);
  m = mn;
}

__device__ inline float wredSum(float v) {
#pragma unroll
  for (int o = 32; o > 0; o >>= 1) v += __shfl_down(v, o, 64);
  return v;
}

__global__ __launch_bounds__(256) void k_ssa(const float* __restrict__ zx,
                                             const float* __restrict__ zy,
                                             float* __restrict__ ws,
                                             float* __restrict__ out) {
  // workspace layout (floats)
  float* rowPM = ws;                    // [16][1024]
  float* rowPS = rowPM + NTB * NN;      // [16][1024]
  float* colPM = rowPS + NTB * NN;      // [16][1024]
  float* colPS = colPM + NTB * MM;      // [16][1024]
  float* rowM  = colPS + NTB * MM;      // [1024]
  float* rowS  = rowM + NN;
  float* colM  = rowS + NN;
  float* colS  = colM + MM;
  float* bNum  = colS + MM;             // [256]
  float* bDen  = bNum + 256;            // [256]

  const int bid = blockIdx.x;
  const int it = bid >> 4;
  const int jt = bid & 15;
  const int i0 = it * TILE, j0 = jt * TILE;
  const int t = threadIdx.x;
  const int tx = t & 15, ty = t >> 4;

  // ---------------- Phase A: 64x64 distance tile in registers ----------------
  float acc4[4][4] = {{0.f}};
  const float4* xp[4];
  const float4* yp[4];
#pragma unroll
  for (int a = 0; a < 4; ++a)
    xp[a] = reinterpret_cast<const float4*>(zx + (size_t)(i0 + ty + a * 16) * DD);
#pragma unroll
  for (int b = 0; b < 4; ++b)
    yp[b] = reinterpret_cast<const float4*>(zy + (size_t)(j0 + tx + b * 16) * DD);

  float4 xv0[4], yv0[4], xv1[4], yv1[4];

#define LOADV(XV, YV, D4)                          \
  {                                                \
    _Pragma("unroll") for (int a = 0; a < 4; ++a)  \
        XV[a] = xp[a][(D4)];                       \
    _Pragma("unroll") for (int b = 0; b < 4; ++b)  \
        YV[b] = yp[b][(D4)];                       \
  }

#define COMPUTEV(XV, YV)                                        \
  {                                                             \
    _Pragma("unroll") for (int a = 0; a < 4; ++a)               \
        _Pragma("unroll") for (int b = 0; b < 4; ++b) {         \
      acc4[a][b] += fabsf(XV[a].x - YV[b].x);                   \
      acc4[a][b] += fabsf(XV[a].y - YV[b].y);                   \
      acc4[a][b] += fabsf(XV[a].z - YV[b].z);                   \
      acc4[a][b] += fabsf(XV[a].w - YV[b].w);                   \
    }                                                           \
  }

  LOADV(xv0, yv0, 0)
  for (int d4 = 0; d4 < DD / 4 - 2; d4 += 2) {
    LOADV(xv1, yv1, d4 + 1)
    COMPUTEV(xv0, yv0)
    LOADV(xv0, yv0, d4 + 2)
    COMPUTEV(xv1, yv1)
  }
  LOADV(xv1, yv1, DD / 4 - 1)
  COMPUTEV(xv0, yv0)
  COMPUTEV(xv1, yv1)
#undef LOADV
#undef COMPUTEV

  // ---------------- Phase B: per-tile row/col softmax partials ----------------
  // row partials: row i = i0 + ty + a*16, reduce over tx (16 lanes) + b
#pragma unroll
  for (int a = 0; a < 4; ++a) {
    float m = -acc4[a][0];
#pragma unroll
    for (int b = 1; b < 4; ++b) m = fmaxf(m, -acc4[a][b]);
    float s = 0.f;
#pragma unroll
    for (int b = 0; b < 4; ++b) s += __expf(-acc4[a][b] - m);
#pragma unroll
    for (int off = 1; off < 16; off <<= 1) {
      float m2 = __shfl_xor(m, off, 64);
      float s2 = __shfl_xor(s, off, 64);
      merge_ms(m, s, m2, s2);
    }
    if (tx == 0) {
      int i = i0 + ty + a * 16;
      rowPM[(size_t)jt * NN + i] = m;
      rowPS[(size_t)jt * NN + i] = s;
    }
  }

  // col partials: col c = tx + b*16 (tile-local), reduce over a + ty (LDS)
  __shared__ float lm[16][64];
  __shared__ float lsv[16][64];
#pragma unroll
  for (int b = 0; b < 4; ++b) {
    int c = tx + b * 16;
    float m = -acc4[0][b];
#pragma unroll
    for (int a = 1; a < 4; ++a) m = fmaxf(m, -acc4[a][b]);
    float s = 0.f;
#pragma unroll
    for (int a = 0; a < 4; ++a) s += __expf(-acc4[a][b] - m);
    lm[ty][c] = m;
    lsv[ty][c] = s;
  }
  __syncthreads();
  if (t < 64) {
    float m = lm[0][t], s = lsv[0][t];
#pragma unroll
    for (int k = 1; k < 16; ++k) merge_ms(m, s, lm[k][t], lsv[k][t]);
    colPM[(size_t)it * MM + j0 + t] = m;
    colPS[(size_t)it * MM + j0 + t] = s;
  }

  cg::grid_group grid = cg::this_grid();
  __threadfence();
  grid.sync();

  // ---------------- Phase C: merge partials into global stats ----------------
  {
    int g = bid * 256 + t;
    if (g < NN) {
      float m = rowPM[g], s = rowPS[g];
#pragma unroll
      for (int k = 1; k < NTB; ++k) merge_ms(m, s, rowPM[(size_t)k * NN + g], rowPS[(size_t)k * NN + g]);
      rowM[g] = m;
      rowS[g] = s;
    } else if (g < 2 * NN) {
      int c = g - NN;
      float m = colPM[c], s = colPS[c];
#pragma unroll
      for (int k = 1; k < NTB; ++k) merge_ms(m, s, colPM[(size_t)k * MM + c], colPS[(size_t)k * MM + c]);
      colM[c] = m;
      colS[c] = s;
    }
  }

  __threadfence();
  grid.sync();

  // ---------------- Phase D: weighted accumulation from registers ----------------
  float rm[4], ri[4], cm[4], ci[4];
#pragma unroll
  for (int a = 0; a < 4; ++a) {
    int i = i0 + ty + a * 16;
    rm[a] = rowM[i];
    ri[a] = 1.f / rowS[i];
  }
#pragma unroll
  for (int b = 0; b < 4; ++b) {
    int j = j0 + tx + b * 16;
    cm[b] = colM[j];
    ci[b] = 1.f / colS[j];
  }
  float num = 0.f, den = 0.f;
#pragma unroll
  for (int a = 0; a < 4; ++a)
#pragma unroll
    for (int b = 0; b < 4; ++b) {
      float s = -acc4[a][b];
      float av = __expf(s - rm[a]) * ri[a];
      float bv = __expf(s - cm[b]) * ci[b];
      float w = av + bv - av * bv;
      num += w * s;
      den += w;
    }
  num = wredSum(num);
  den = wredSum(den);
  __shared__ float rn[4], rd[4];
  const int lane = t & 63, wv = t >> 6;
  if (lane == 0) {
    rn[wv] = num;
    rd[wv] = den;
  }
  __syncthreads();
  if (t == 0) {
    bNum[bid] = rn[0] + rn[1] + rn[2] + rn[3];
    bDen[bid] = rd[0] + rd[1] + rd[2] + rd[3];
  }

  __threadfence();
  grid.sync();

  // ---------------- Phase E: final reduce by block 0 ----------------
  if (bid == 0) {
    float n = bNum[t], d = bDen[t];
    n = wredSum(n);
    d = wredSum(d);
    if (lane == 0) {
      rn[wv] = n;
      rd[wv] = d;
    }
    __syncthreads();
    if (t == 0) out[0] = (rn[0] + rn[1] + rn[2] + rn[3]) / (rd[0] + rd[1] + rd[2] + rd[3]);
  }
}

extern "C" void kernel_launch(void* const* d_in, const int* in_sizes, int n_in,
                              void* d_out, int out_size, void* d_ws, size_t ws_size,
                              hipStream_t stream) {
  const float* zx = (const float*)d_in[0];
  const float* zy = (const float*)d_in[1];
  float* out = (float*)d_out;
  float* ws = (float*)d_ws;

  void* args[] = {(void*)&zx, (void*)&zy, (void*)&ws, (void*)&out};
  hipLaunchCooperativeKernel((const void*)k_ssa, dim3(256), dim3(256), args, 0, stream);
}

// Round 4
// 39.200 us; speedup vs baseline: 5.3317x; 5.3317x over previous
//
#include <hip/hip_runtime.h>
#include <math.h>

#define NN 1024
#define MM 1024
#define DD 256
#define TILE 64
#define NTB 16
#define PITCH 260  // 256 + 4 pad: conflict-free b128 reads (proven in R1)

__device__ inline void merge_ms(float& m, float& s, float m2, float s2) {
  float mn = fmaxf(m, m2);
  s = s * __expf(m - mn) + s2 * __expf(m2 - mn);
  m = mn;
}

__device__ inline float wredSum(float v) {
#pragma unroll
  for (int o = 32; o > 0; o >>= 1) v += __shfl_down(v, o, 64);
  return v;
}

// ---------------- K1: distance tile + S store + row/col softmax partials ----
__global__ __launch_bounds__(256) void k_tile(const float* __restrict__ zx,
                                              const float* __restrict__ zy,
                                              float* __restrict__ S,
                                              float* __restrict__ rowPM,
                                              float* __restrict__ rowPS,
                                              float* __restrict__ colPM,
                                              float* __restrict__ colPS) {
  __shared__ float xs[TILE * PITCH];
  __shared__ float ys[TILE * PITCH];
  const int it = blockIdx.y, jt = blockIdx.x;
  const int i0 = it * TILE, j0 = jt * TILE;
  const int t = threadIdx.x;
  const int tx = t & 15, ty = t >> 4;

  // stage 64 rows x 256 floats of both inputs (R1-proven, coalesced float4)
#pragma unroll
  for (int k = 0; k < 16; ++k) {
    int idx4 = t + k * 256;
    int r = idx4 >> 6;
    int c4 = idx4 & 63;
    float4 vx = reinterpret_cast<const float4*>(zx + (size_t)(i0 + r) * DD)[c4];
    float4 vy = reinterpret_cast<const float4*>(zy + (size_t)(j0 + r) * DD)[c4];
    *reinterpret_cast<float4*>(&xs[r * PITCH + c4 * 4]) = vx;
    *reinterpret_cast<float4*>(&ys[r * PITCH + c4 * 4]) = vy;
  }
  __syncthreads();

  float acc4[4][4] = {{0.f}};
  for (int d4 = 0; d4 < DD / 4; ++d4) {
    float4 xa[4], yb[4];
#pragma unroll
    for (int a = 0; a < 4; ++a)
      xa[a] = *reinterpret_cast<const float4*>(&xs[(ty + a * 16) * PITCH + d4 * 4]);
#pragma unroll
    for (int b = 0; b < 4; ++b)
      yb[b] = *reinterpret_cast<const float4*>(&ys[(tx + b * 16) * PITCH + d4 * 4]);
#pragma unroll
    for (int a = 0; a < 4; ++a)
#pragma unroll
      for (int b = 0; b < 4; ++b) {
        acc4[a][b] += fabsf(xa[a].x - yb[b].x) + fabsf(xa[a].y - yb[b].y) +
                      fabsf(xa[a].z - yb[b].z) + fabsf(xa[a].w - yb[b].w);
      }
  }

  // store S tile (R1-proven layout)
#pragma unroll
  for (int a = 0; a < 4; ++a) {
    int i = i0 + ty + a * 16;
#pragma unroll
    for (int b = 0; b < 4; ++b) {
      int j = j0 + tx + b * 16;
      S[(size_t)i * MM + j] = -acc4[a][b];
    }
  }

  // row partials (R2-proven): row i = i0 + ty + a*16, reduce over tx lanes + b
#pragma unroll
  for (int a = 0; a < 4; ++a) {
    float m = -acc4[a][0];
#pragma unroll
    for (int b = 1; b < 4; ++b) m = fmaxf(m, -acc4[a][b]);
    float s = 0.f;
#pragma unroll
    for (int b = 0; b < 4; ++b) s += __expf(-acc4[a][b] - m);
#pragma unroll
    for (int off = 1; off < 16; off <<= 1) {
      float m2 = __shfl_xor(m, off, 64);
      float s2 = __shfl_xor(s, off, 64);
      merge_ms(m, s, m2, s2);
    }
    if (tx == 0) {
      int i = i0 + ty + a * 16;
      rowPM[(size_t)jt * NN + i] = m;
      rowPS[(size_t)jt * NN + i] = s;
    }
  }

  // col partials (R2-proven): col c = tx + b*16, reduce over a regs + ty via LDS
  __shared__ float lm[16][64];
  __shared__ float lsv[16][64];
#pragma unroll
  for (int b = 0; b < 4; ++b) {
    int c = tx + b * 16;
    float m = -acc4[0][b];
#pragma unroll
    for (int a = 1; a < 4; ++a) m = fmaxf(m, -acc4[a][b]);
    float s = 0.f;
#pragma unroll
    for (int a = 0; a < 4; ++a) s += __expf(-acc4[a][b] - m);
    lm[ty][c] = m;
    lsv[ty][c] = s;
  }
  __syncthreads();
  if (t < 64) {
    float m = lm[0][t], s = lsv[0][t];
#pragma unroll
    for (int k = 1; k < 16; ++k) merge_ms(m, s, lm[k][t], lsv[k][t]);
    colPM[(size_t)it * MM + j0 + t] = m;
    colPS[(size_t)it * MM + j0 + t] = s;
  }
}

// ---------------- K2: merge 16 stripe partials -> global stats ----------------
__global__ __launch_bounds__(256) void k_merge(const float* __restrict__ rowPM,
                                               const float* __restrict__ rowPS,
                                               const float* __restrict__ colPM,
                                               const float* __restrict__ colPS,
                                               float* __restrict__ rowM,
                                               float* __restrict__ rowS,
                                               float* __restrict__ colM,
                                               float* __restrict__ colS) {
  int g = blockIdx.x * 256 + threadIdx.x;  // grid 8 -> g in [0, 2048)
  if (g < NN) {
    float m = rowPM[g], s = rowPS[g];
#pragma unroll
    for (int k = 1; k < NTB; ++k)
      merge_ms(m, s, rowPM[(size_t)k * NN + g], rowPS[(size_t)k * NN + g]);
    rowM[g] = m;
    rowS[g] = s;
  } else {
    int c = g - NN;
    float m = colPM[c], s = colPS[c];
#pragma unroll
    for (int k = 1; k < NTB; ++k)
      merge_ms(m, s, colPM[(size_t)k * MM + c], colPS[(size_t)k * MM + c]);
    colM[c] = m;
    colS[c] = s;
  }
}

// ---------------- K3: weighted accumulation, per-row-block partials ----------
__global__ __launch_bounds__(256) void k_accum(const float* __restrict__ S,
                                               const float* __restrict__ rowM,
                                               const float* __restrict__ rowS,
                                               const float* __restrict__ colM,
                                               const float* __restrict__ colS,
                                               float* __restrict__ bNum,
                                               float* __restrict__ bDen) {
  const int i = blockIdx.x;
  const int t = threadIdx.x;
  float4 v = reinterpret_cast<const float4*>(S + (size_t)i * MM)[t];
  const float rm = rowM[i];
  const float rinv = 1.f / rowS[i];
  float4 cm = reinterpret_cast<const float4*>(colM)[t];
  float4 cs = reinterpret_cast<const float4*>(colS)[t];
  float num = 0.f, den = 0.f;
#define DO_COMP(VX, CMX, CSX)               \
  {                                         \
    float a = __expf((VX) - rm) * rinv;     \
    float b = __expf((VX) - (CMX)) / (CSX); \
    float w = a + b - a * b;                \
    num += w * (VX);                        \
    den += w;                               \
  }
  DO_COMP(v.x, cm.x, cs.x)
  DO_COMP(v.y, cm.y, cs.y)
  DO_COMP(v.z, cm.z, cs.z)
  DO_COMP(v.w, cm.w, cs.w)
#undef DO_COMP
  num = wredSum(num);
  den = wredSum(den);
  __shared__ float rn[4], rd[4];
  const int lane = t & 63, wv = t >> 6;
  if (lane == 0) { rn[wv] = num; rd[wv] = den; }
  __syncthreads();
  if (t == 0) {
    bNum[i] = rn[0] + rn[1] + rn[2] + rn[3];
    bDen[i] = rd[0] + rd[1] + rd[2] + rd[3];
  }
}

// ---------------- K4: final reduce + divide ----------------
__global__ __launch_bounds__(256) void k_final(const float* __restrict__ bNum,
                                               const float* __restrict__ bDen,
                                               float* __restrict__ out) {
  const int t = threadIdx.x;
  float4 n4 = reinterpret_cast<const float4*>(bNum)[t];
  float4 d4 = reinterpret_cast<const float4*>(bDen)[t];
  float n = n4.x + n4.y + n4.z + n4.w;
  float d = d4.x + d4.y + d4.z + d4.w;
  n = wredSum(n);
  d = wredSum(d);
  __shared__ float rn[4], rd[4];
  const int lane = t & 63, wv = t >> 6;
  if (lane == 0) { rn[wv] = n; rd[wv] = d; }
  __syncthreads();
  if (t == 0) out[0] = (rn[0] + rn[1] + rn[2] + rn[3]) / (rd[0] + rd[1] + rd[2] + rd[3]);
}

// ---------------- launch ----------------
extern "C" void kernel_launch(void* const* d_in, const int* in_sizes, int n_in,
                              void* d_out, int out_size, void* d_ws, size_t ws_size,
                              hipStream_t stream) {
  const float* zx = (const float*)d_in[0];
  const float* zy = (const float*)d_in[1];
  float* out = (float*)d_out;

  float* ws = (float*)d_ws;
  float* S     = ws;                        // 1M floats (16B-aligned offsets below)
  float* rowPM = S + (size_t)NN * MM;       // 16K
  float* rowPS = rowPM + NTB * NN;          // 16K
  float* colPM = rowPS + NTB * NN;          // 16K
  float* colPS = colPM + NTB * MM;          // 16K
  float* rowM  = colPS + NTB * MM;          // 1K
  float* rowS  = rowM + NN;                 // 1K
  float* colM  = rowS + NN;                 // 1K
  float* colS  = colM + MM;                 // 1K
  float* bNum  = colS + MM;                 // 1K
  float* bDen  = bNum + NN;                 // 1K

  k_tile<<<dim3(NTB, NTB), 256, 0, stream>>>(zx, zy, S, rowPM, rowPS, colPM, colPS);
  k_merge<<<8, 256, 0, stream>>>(rowPM, rowPS, colPM, colPS, rowM, rowS, colM, colS);
  k_accum<<<NN, 256, 0, stream>>>(S, rowM, rowS, colM, colS, bNum, bDen);
  k_final<<<1, 256, 0, stream>>>(bNum, bDen, out);
}